// Round 17
// baseline (26.157 us; speedup 1.0000x reference)
//
#include <hip/hip_runtime.h>
#include <math.h>

#define E_CNT 1999
#define N_PTS 2000
#define B_CNT 8
#define SEG 2048                           // X edges in [0,SEG), target edges in [SEG,2*SEG)
#define NTILES 16                          // 256-row tiles
#define NTP 136                            // upper-triangle tile pairs
#define TOTAL_BLOCKS (B_CNT*NTP)           // 1088

#define HCEXP (-2.8853900817779268f)       // -2*log2(e)
#define SQRT_NEG2C 3.3972871f              // sqrt(8*log2(e))

typedef __attribute__((ext_vector_type(8))) _Float16 half8;
typedef __attribute__((ext_vector_type(4))) float f32x4;
typedef __attribute__((ext_vector_type(4))) int i32x4;

__device__ __forceinline__ half8 mk_frag(int lo, int hi) {
    i32x4 t; t[0] = lo; t[1] = hi; t[2] = 0; t[3] = 0;
    return __builtin_bit_cast(half8, t);
}

// f16 edge record for slot of sample b:
//   halves [ s*cx, s*cy, s*cz, 0, u''x, u''y, u''z, 0 ],  s = sqrt(NEG2C),
//   u'' = (t/sqrt(l)) * exp2(HCEXP*|c|^2).  Pads all-zero.
// diagResp: also return l^2 + SRNF(X) - selfterm (f32 recomputation of the
// MFMA self-pair from ROUNDED f16 values — cancels the in-tile diagonal).
__device__ __forceinline__ float edge_rec(
    const float* __restrict__ outp, const float* __restrict__ tgtp,
    const float* __restrict__ tmpl, int b, int slot, bool diagResp,
    i32x4& rec)
{
    float val = 0.f;
    bool isX = (slot < SEG);
    int e = isX ? slot : slot - SEG;
    if (e < E_CNT) {
        float ax, ay, az, bx, by, bz;
        if (isX) {
            const float* o0 = outp + ((size_t)b * N_PTS + e) * 3;
            const float* t0 = tmpl + (size_t)e * 3;
            ax = o0[0] + t0[0]; ay = o0[1] + t0[1]; az = o0[2] + t0[2];
            bx = o0[3] + t0[3]; by = o0[4] + t0[4]; bz = o0[5] + t0[5];
        } else {
            const float* g0 = tgtp + ((size_t)b * N_PTS + e) * 3;
            ax = g0[0]; ay = g0[1]; az = g0[2];
            bx = g0[3]; by = g0[4]; bz = g0[5];
        }
        float cx = 0.5f * (ax + bx), cy = 0.5f * (ay + by), cz = 0.5f * (az + bz);
        float tx = bx - ax, ty = by - ay, tz = bz - az;
        float l2 = tx * tx + ty * ty + tz * tz + 1e-12f;
        float l  = sqrtf(l2);
        float rs = rsqrtf(l);
        float f  = __builtin_amdgcn_exp2f(HCEXP * (cx * cx + cy * cy + cz * cz));
        float g  = rs * f;
        half8 hv;
        hv[0] = (_Float16)(SQRT_NEG2C * cx);
        hv[1] = (_Float16)(SQRT_NEG2C * cy);
        hv[2] = (_Float16)(SQRT_NEG2C * cz);
        hv[3] = (_Float16)0.f;
        hv[4] = (_Float16)(tx * g);
        hv[5] = (_Float16)(ty * g);
        hv[6] = (_Float16)(tz * g);
        hv[7] = (_Float16)0.f;
        rec = __builtin_bit_cast(i32x4, hv);
        if (diagResp) {
            float a0 = (float)hv[0], a1 = (float)hv[1], a2 = (float)hv[2];
            float d0 = (float)hv[4], d1 = (float)hv[5], d2 = (float)hv[6];
            float sarg = a0 * a0 + a1 * a1 + a2 * a2;
            float sdu  = d0 * d0 + d1 * d1 + d2 * d2;
            float self = __builtin_amdgcn_exp2f(sarg) * sdu * sdu;
            val = l * l - self;
            if (isX) {
                const float* t0 = tmpl + (size_t)e * 3;
                float txT = t0[3] - t0[0], tyT = t0[4] - t0[1], tzT = t0[5] - t0[2];
                float lT = sqrtf(txT * txT + tyT * tyT + tzT * tzT + 1e-12f);
                float rT = rsqrtf(lT);
                float dqx = tx * rs - txT * rT;     // q = t/sqrt(l)
                float dqy = ty * rs - tyT * rT;
                float dqz = tz * rs - tzT * rT;
                val += 1e-7f * (dqx * dqx + dqy * dqy + dqz * dqz);
            }
        }
    } else {
        i32x4 z; z[0] = 0; z[1] = 0; z[2] = 0; z[3] = 0;
        rec = z;
    }
    return val;
}

// R14 tiling, 16-wave blocks (1024 threads), one block per (sample,
// tile-pair).  Each wave owns ONE 16-row tile x 16 ctiles.  The ctile loop
// is software-pipelined 1-deep: ctile k+1's LDS read + 2 MFMAs are issued
// BEFORE ctile k's exp2/mul/fma consume — trans work overlaps matrix-pipe
// latency.  Work and math bit-identical to R16.
__global__ __launch_bounds__(1024) void fused_kernel(
    const float* __restrict__ outp, const float* __restrict__ tgtp,
    const float* __restrict__ tmpl, float* __restrict__ part)
{
    __shared__ i32x4 sRec[513];    // [0,256) rows, [256,512) cols, [512] zero
    __shared__ float red[16];

    int id = blockIdx.x;
    int b  = id / NTP;
    int t  = id % NTP;
    int rt = 0, rem = t;
    while (rem >= NTILES - rt) { rem -= NTILES - rt; ++rt; }
    int ct = rt + rem;

    int tid = threadIdx.x, lane = tid & 63, w = tid >> 6;
    bool isDiag = (rt == ct);

    // stage: threads <256 -> rows (with diag term); [256,512) -> cols
    float dval = 0.f;
    if (tid < 256) {
        i32x4 rrec;
        dval = edge_rec(outp, tgtp, tmpl, b, rt * 256 + tid, isDiag, rrec);
        sRec[tid] = rrec;
    } else if (tid < 512) {
        int c = tid - 256;
        i32x4 crec;
        edge_rec(outp, tgtp, tmpl, b, ct * 256 + c, false, crec);
        sRec[256 + c] = crec;
    } else if (tid == 512) {
        i32x4 z; z[0] = 0; z[1] = 0; z[2] = 0; z[3] = 0;
        sRec[512] = z;
    }
    __syncthreads();

    int l15 = lane & 15;
    bool g0 = (lane < 16);            // lanes >=16 carry k>=8 (all zero)

    // A-side fragment for this wave's single row-tile
    half8 aArg, aDu;
    {
        i32x4 ra = sRec[g0 ? (w * 16 + l15) : 512];
        aArg = mk_frag(ra[0], ra[1]);
        aDu  = mk_frag(ra[2], ra[3]);
    }

    const f32x4 zz = {0.f, 0.f, 0.f, 0.f};
    f32x4 av = {0.f, 0.f, 0.f, 0.f};

    // pipeline prologue: ctile 0's MFMAs in flight
    f32x4 dA, dD;
    {
        i32x4 rb = sRec[g0 ? (256 + l15) : 512];
        dA = __builtin_amdgcn_mfma_f32_16x16x32_f16(aArg, mk_frag(rb[0], rb[1]), zz, 0, 0, 0);
        dD = __builtin_amdgcn_mfma_f32_16x16x32_f16(aDu,  mk_frag(rb[2], rb[3]), zz, 0, 0, 0);
    }
    #pragma unroll
    for (int ctile = 0; ctile < 16; ++ctile) {
        f32x4 cA = dA, cD = dD;
        if (ctile < 15) {               // issue next ctile's MFMAs first
            i32x4 rb = sRec[g0 ? (256 + (ctile + 1) * 16 + l15) : 512];
            dA = __builtin_amdgcn_mfma_f32_16x16x32_f16(aArg, mk_frag(rb[0], rb[1]), zz, 0, 0, 0);
            dD = __builtin_amdgcn_mfma_f32_16x16x32_f16(aDu,  mk_frag(rb[2], rb[3]), zz, 0, 0, 0);
        }
        #pragma unroll
        for (int rr = 0; rr < 4; ++rr)  // consume current ctile
            av[rr] = fmaf(__builtin_amdgcn_exp2f(cA[rr]), cD[rr] * cD[rr], av[rr]);
    }

    // diag tile-pair x1 (self-pairs cancelled via selfterm in dval);
    // off-diag x2; cross-segment negative.
    float sgn = isDiag ? 1.f : (((rt < 8) == (ct < 8)) ? 2.f : -2.f);
    float thr = fmaf(sgn, (av[0] + av[1]) + (av[2] + av[3]), dval);
    for (int off = 32; off; off >>= 1) thr += __shfl_down(thr, off);
    if (lane == 0) red[w] = thr;
    __syncthreads();
    if (tid == 0) {
        float s = 0.f;
        #pragma unroll
        for (int i = 0; i < 16; ++i) s += red[i];
        part[id] = s;
    }
}

__global__ __launch_bounds__(256) void final_kernel(
    const float* __restrict__ part, float* __restrict__ outv)
{
    float s = 0.f;
    for (int i = threadIdx.x; i < TOTAL_BLOCKS; i += 256) s += part[i];
    for (int off = 32; off; off >>= 1) s += __shfl_down(s, off);
    __shared__ float red[4];
    int lane = threadIdx.x & 63, wid = threadIdx.x >> 6;
    if (lane == 0) red[wid] = s;
    __syncthreads();
    if (threadIdx.x == 0)
        outv[0] = 0.125f * ((red[0] + red[1]) + (red[2] + red[3]));
}

extern "C" void kernel_launch(void* const* d_in, const int* in_sizes, int n_in,
                              void* d_out, int out_size, void* d_ws, size_t ws_size,
                              hipStream_t stream)
{
    const float* outp = (const float*)d_in[0];  // (8,2000,3) f32
    const float* tgtp = (const float*)d_in[1];  // (8,2000,3) f32
    const float* tmpl = (const float*)d_in[3];  // (2000,3) f32
    float* part = (float*)d_ws;                 // TOTAL_BLOCKS floats, all written each launch

    fused_kernel<<<TOTAL_BLOCKS, 1024, 0, stream>>>(outp, tgtp, tmpl, part);
    final_kernel<<<1, 256, 0, stream>>>(part, (float*)d_out);
}

// Round 18
// 21.446 us; speedup vs baseline: 1.2197x; 1.2197x over previous
//
#include <hip/hip_runtime.h>
#include <math.h>

#define E_CNT 1999
#define N_PTS 2000
#define B_CNT 8
#define SEG 2048                           // X edges in [0,SEG), target edges in [SEG,2*SEG)
#define NTILES 16                          // 256-row tiles
#define NTP 136                            // upper-triangle tile pairs
#define TOTAL_BLOCKS (B_CNT*NTP)           // 1088

#define HCEXP (-2.8853900817779268f)       // -2*log2(e)
#define SQRT_NEG2C 3.3972871f              // sqrt(8*log2(e))

typedef __attribute__((ext_vector_type(8))) _Float16 half8;
typedef __attribute__((ext_vector_type(4))) float f32x4;
typedef __attribute__((ext_vector_type(16))) float f32x16;
typedef __attribute__((ext_vector_type(4))) int i32x4;

__device__ __forceinline__ half8 mk_frag(int lo, int hi) {
    i32x4 t; t[0] = lo; t[1] = hi; t[2] = 0; t[3] = 0;
    return __builtin_bit_cast(half8, t);
}

// f16 edge record for slot of sample b:
//   halves [ s*cx, s*cy, s*cz, 0, u''x, u''y, u''z, 0 ],  s = sqrt(NEG2C),
//   u'' = (t/sqrt(l)) * exp2(HCEXP*|c|^2).  Pads all-zero.
// diagResp: also return l^2 + SRNF(X) - selfterm (f32 recomputation of the
// MFMA self-pair from ROUNDED f16 values — cancels the in-tile diagonal).
__device__ __forceinline__ float edge_rec(
    const float* __restrict__ outp, const float* __restrict__ tgtp,
    const float* __restrict__ tmpl, int b, int slot, bool diagResp,
    i32x4& rec)
{
    float val = 0.f;
    bool isX = (slot < SEG);
    int e = isX ? slot : slot - SEG;
    if (e < E_CNT) {
        float ax, ay, az, bx, by, bz;
        if (isX) {
            const float* o0 = outp + ((size_t)b * N_PTS + e) * 3;
            const float* t0 = tmpl + (size_t)e * 3;
            ax = o0[0] + t0[0]; ay = o0[1] + t0[1]; az = o0[2] + t0[2];
            bx = o0[3] + t0[3]; by = o0[4] + t0[4]; bz = o0[5] + t0[5];
        } else {
            const float* g0 = tgtp + ((size_t)b * N_PTS + e) * 3;
            ax = g0[0]; ay = g0[1]; az = g0[2];
            bx = g0[3]; by = g0[4]; bz = g0[5];
        }
        float cx = 0.5f * (ax + bx), cy = 0.5f * (ay + by), cz = 0.5f * (az + bz);
        float tx = bx - ax, ty = by - ay, tz = bz - az;
        float l2 = tx * tx + ty * ty + tz * tz + 1e-12f;
        float l  = sqrtf(l2);
        float rs = rsqrtf(l);
        float f  = __builtin_amdgcn_exp2f(HCEXP * (cx * cx + cy * cy + cz * cz));
        float g  = rs * f;
        half8 hv;
        hv[0] = (_Float16)(SQRT_NEG2C * cx);
        hv[1] = (_Float16)(SQRT_NEG2C * cy);
        hv[2] = (_Float16)(SQRT_NEG2C * cz);
        hv[3] = (_Float16)0.f;
        hv[4] = (_Float16)(tx * g);
        hv[5] = (_Float16)(ty * g);
        hv[6] = (_Float16)(tz * g);
        hv[7] = (_Float16)0.f;
        rec = __builtin_bit_cast(i32x4, hv);
        if (diagResp) {
            float a0 = (float)hv[0], a1 = (float)hv[1], a2 = (float)hv[2];
            float d0 = (float)hv[4], d1 = (float)hv[5], d2 = (float)hv[6];
            float sarg = a0 * a0 + a1 * a1 + a2 * a2;
            float sdu  = d0 * d0 + d1 * d1 + d2 * d2;
            float self = __builtin_amdgcn_exp2f(sarg) * sdu * sdu;
            val = l * l - self;
            if (isX) {
                const float* t0 = tmpl + (size_t)e * 3;
                float txT = t0[3] - t0[0], tyT = t0[4] - t0[1], tzT = t0[5] - t0[2];
                float lT = sqrtf(txT * txT + tyT * tyT + tzT * tzT + 1e-12f);
                float rT = rsqrtf(lT);
                float dqx = tx * rs - txT * rT;     // q = t/sqrt(l)
                float dqy = ty * rs - tyT * rT;
                float dqz = tz * rs - tzT * rT;
                val += 1e-7f * (dqx * dqx + dqy * dqy + dqz * dqz);
            }
        }
    } else {
        i32x4 z; z[0] = 0; z[1] = 0; z[2] = 0; z[3] = 0;
        rec = z;
    }
    return val;
}

// R16 block shape (512 thr / 8 waves, one block per (sample, tile-pair)),
// but 32x32x16 MFMA: each wave owns a 32-row band x 8 col-tiles of 32.
// One MFMA pair -> 1024 pairs and 16 independent exp2->fma chains per lane
// (vs 4 with 16x16) — amortizes matrix-pipe latency 4x, plus 4x fewer MFMA
// issues / LDS reads / frag builds.  Math identical: lanes 0-31 carry k=0-7
// (rank-3 data + zero pad), lanes 32-63 zero (k=8-15); outputs are summed,
// never indexed, so the result is invariant to fragment-layout details
// (symmetric matrices, identical records).  Diag self-pairs cancelled via
// the f16-rounded selfterm in dval (exact-once, rows staged once).
__global__ __launch_bounds__(512) void fused_kernel(
    const float* __restrict__ outp, const float* __restrict__ tgtp,
    const float* __restrict__ tmpl, float* __restrict__ part)
{
    __shared__ i32x4 sRec[513];    // [0,256) rows, [256,512) cols, [512] zero
    __shared__ float red[8];

    int id = blockIdx.x;
    int b  = id / NTP;
    int t  = id % NTP;
    int rt = 0, rem = t;
    while (rem >= NTILES - rt) { rem -= NTILES - rt; ++rt; }
    int ct = rt + rem;

    int tid = threadIdx.x, lane = tid & 63, w = tid >> 6;
    bool isDiag = (rt == ct);

    // stage: threads <256 -> rows (with diag term), threads >=256 -> cols
    float dval = 0.f;
    if (tid < 256) {
        i32x4 rrec;
        dval = edge_rec(outp, tgtp, tmpl, b, rt * 256 + tid, isDiag, rrec);
        sRec[tid] = rrec;
    } else {
        int c = tid - 256;
        i32x4 crec;
        edge_rec(outp, tgtp, tmpl, b, ct * 256 + c, false, crec);
        sRec[256 + c] = crec;
    }
    if (tid == 0) {
        i32x4 z; z[0] = 0; z[1] = 0; z[2] = 0; z[3] = 0;
        sRec[512] = z;
    }
    __syncthreads();

    int li = lane & 31;
    bool lo32 = (lane < 32);          // lanes >=32 carry k>=8 (all zero)

    // A-side fragments for this wave's 32-row band — built once
    i32x4 ra = sRec[lo32 ? (w * 32 + li) : 512];
    half8 aArg = mk_frag(ra[0], ra[1]);
    half8 aDu  = mk_frag(ra[2], ra[3]);

    const f32x16 zz = {0.f,0.f,0.f,0.f,0.f,0.f,0.f,0.f,
                       0.f,0.f,0.f,0.f,0.f,0.f,0.f,0.f};
    f32x4 av = {0.f, 0.f, 0.f, 0.f};

    #pragma unroll
    for (int c = 0; c < 8; ++c) {
        i32x4 rb = sRec[lo32 ? (256 + c * 32 + li) : 512];
        half8 bArg = mk_frag(rb[0], rb[1]);
        half8 bDu  = mk_frag(rb[2], rb[3]);
        f32x16 dA = __builtin_amdgcn_mfma_f32_32x32x16_f16(aArg, bArg, zz, 0, 0, 0);
        f32x16 dD = __builtin_amdgcn_mfma_f32_32x32x16_f16(aDu,  bDu,  zz, 0, 0, 0);
        #pragma unroll
        for (int rr = 0; rr < 16; ++rr)
            av[rr & 3] = fmaf(__builtin_amdgcn_exp2f(dA[rr]), dD[rr] * dD[rr], av[rr & 3]);
    }

    // diag tile-pair x1 (self-pairs cancelled via selfterm in dval);
    // off-diag x2; cross-segment negative.
    float sgn = isDiag ? 1.f : (((rt < 8) == (ct < 8)) ? 2.f : -2.f);
    float thr = fmaf(sgn, (av[0] + av[1]) + (av[2] + av[3]), dval);
    for (int off = 32; off; off >>= 1) thr += __shfl_down(thr, off);
    if (lane == 0) red[w] = thr;
    __syncthreads();
    if (tid == 0) {
        float s = ((red[0] + red[1]) + (red[2] + red[3]))
                + ((red[4] + red[5]) + (red[6] + red[7]));
        part[id] = s;
    }
}

__global__ __launch_bounds__(256) void final_kernel(
    const float* __restrict__ part, float* __restrict__ outv)
{
    float s = 0.f;
    for (int i = threadIdx.x; i < TOTAL_BLOCKS; i += 256) s += part[i];
    for (int off = 32; off; off >>= 1) s += __shfl_down(s, off);
    __shared__ float red[4];
    int lane = threadIdx.x & 63, wid = threadIdx.x >> 6;
    if (lane == 0) red[wid] = s;
    __syncthreads();
    if (threadIdx.x == 0)
        outv[0] = 0.125f * ((red[0] + red[1]) + (red[2] + red[3]));
}

extern "C" void kernel_launch(void* const* d_in, const int* in_sizes, int n_in,
                              void* d_out, int out_size, void* d_ws, size_t ws_size,
                              hipStream_t stream)
{
    const float* outp = (const float*)d_in[0];  // (8,2000,3) f32
    const float* tgtp = (const float*)d_in[1];  // (8,2000,3) f32
    const float* tmpl = (const float*)d_in[3];  // (2000,3) f32
    float* part = (float*)d_ws;                 // TOTAL_BLOCKS floats, all written each launch

    fused_kernel<<<TOTAL_BLOCKS, 512, 0, stream>>>(outp, tgtp, tmpl, part);
    final_kernel<<<1, 256, 0, stream>>>(part, (float*)d_out);
}